// Round 1
// baseline (20475.748 us; speedup 1.0000x reference)
//
#include <hip/hip_runtime.h>
#include <math.h>

#define UNITS 1024
#define FEAT 128
#define TSEQ 48
#define BATCH 2048
#define OUT_STEPS 24
#define KTOT (FEAT + UNITS)   // 1152
#define N4 (4 * UNITS)        // 4096

#define BM 64
#define BN 64
#define BK 16

// Z[b][n] = sum_k X[b][k]*W[k][n] + sum_k H[b][k]*U[k][n]
// X has row stride xstride (elements). W: [FEAT][N4], U: [UNITS][N4].
__global__ __launch_bounds__(256)
void gemm_z_kernel(const float* __restrict__ X, int xstride,
                   const float* __restrict__ H,
                   const float* __restrict__ W,
                   const float* __restrict__ U,
                   float* __restrict__ Z) {
  __shared__ float As[BK][BM + 4];  // transposed A tile; +4 pad keeps 16B align & breaks conflicts
  __shared__ float Bs[BK][BN];
  const int bm = blockIdx.x * BM;
  const int bn = blockIdx.y * BN;
  const int tid = threadIdx.x;
  const int tx = tid & 15;   // col group (4 cols each)
  const int ty = tid >> 4;   // row group (4 rows each)

  float acc[4][4] = {};

  for (int k0 = 0; k0 < KTOT; k0 += BK) {
    // ---- stage A tile (BM x BK) transposed into As[k][row] ----
    {
      const int k = tid & 15;
      const int rbase = tid >> 4;
      const bool isx = (k0 < FEAT);
#pragma unroll
      for (int p = 0; p < 4; ++p) {
        const int row = p * 16 + rbase;
        float v;
        if (isx) v = X[(size_t)(bm + row) * xstride + (k0 + k)];
        else     v = H[(size_t)(bm + row) * UNITS + (k0 - FEAT + k)];
        As[k][row] = v;
      }
    }
    // ---- stage B tile (BK x BN) ----
    {
      const int k = tid >> 4;
      const int n = (tid & 15) * 4;
      const float* src = (k0 < FEAT)
          ? (W + (size_t)(k0 + k) * N4 + bn + n)
          : (U + (size_t)(k0 - FEAT + k) * N4 + bn + n);
      *reinterpret_cast<float4*>(&Bs[k][n]) = *reinterpret_cast<const float4*>(src);
    }
    __syncthreads();

#pragma unroll
    for (int kk = 0; kk < BK; ++kk) {
      const float4 av = *reinterpret_cast<const float4*>(&As[kk][ty * 4]);
      const float4 bv = *reinterpret_cast<const float4*>(&Bs[kk][tx * 4]);
      const float a[4] = {av.x, av.y, av.z, av.w};
      const float b[4] = {bv.x, bv.y, bv.z, bv.w};
#pragma unroll
      for (int i = 0; i < 4; ++i)
#pragma unroll
        for (int j = 0; j < 4; ++j)
          acc[i][j] += a[i] * b[j];
    }
    __syncthreads();
  }

#pragma unroll
  for (int i = 0; i < 4; ++i) {
    float4 v = make_float4(acc[i][0], acc[i][1], acc[i][2], acc[i][3]);
    *reinterpret_cast<float4*>(&Z[(size_t)(bm + ty * 4 + i) * N4 + bn + tx * 4]) = v;
  }
}

// Gate nonlinearity + state update. Gate order i,f,g,o in column blocks of UNITS.
__global__ __launch_bounds__(256)
void gates_kernel(const float* __restrict__ Z, const float* __restrict__ bias,
                  float* __restrict__ h, float* __restrict__ c) {
  const int idx = blockIdx.x * 256 + threadIdx.x;  // 0 .. BATCH*UNITS-1
  const int b = idx >> 10;
  const int u = idx & 1023;
  const float* zrow = Z + (size_t)b * N4;
  const float zi = zrow[u]             + bias[u];
  const float zf = zrow[UNITS + u]     + bias[UNITS + u];
  const float zg = zrow[2 * UNITS + u] + bias[2 * UNITS + u];
  const float zo = zrow[3 * UNITS + u] + bias[3 * UNITS + u];
  const float gi = 1.0f / (1.0f + expf(-zi));
  const float gf = 1.0f / (1.0f + expf(-zf));
  const float gg = tanhf(zg);
  const float go = 1.0f / (1.0f + expf(-zo));
  const float c_new = gf * c[idx] + gi * gg;
  c[idx] = c_new;
  h[idx] = go * tanhf(c_new);
}

// y[b][j] = h[b] . dense_w[:,j] + dense_b[j]; also writes the output slice
// (S0:S1 == 0:128 is the full dense output).
__global__ __launch_bounds__(256)
void dense_kernel(const float* __restrict__ h, const float* __restrict__ Wd,
                  const float* __restrict__ bd, float* __restrict__ y,
                  float* __restrict__ out, int step) {
  __shared__ float hs[2][UNITS];
  const int tid = threadIdx.x;
  const int r = tid >> 7;   // 0..1
  const int j = tid & 127;
  const int brow = blockIdx.x * 2;

#pragma unroll
  for (int p = 0; p < 8; ++p) {
    const int li = p * 256 + tid;  // 0..2047
    hs[li >> 10][li & 1023] = h[(size_t)(brow + (li >> 10)) * UNITS + (li & 1023)];
  }
  __syncthreads();

  float acc = bd[j];
#pragma unroll 8
  for (int k = 0; k < UNITS; ++k) {
    acc += hs[r][k] * Wd[(size_t)k * FEAT + j];
  }
  const int b = brow + r;
  y[(size_t)b * FEAT + j] = acc;
  out[((size_t)b * OUT_STEPS + step) * FEAT + j] = acc;
}

extern "C" void kernel_launch(void* const* d_in, const int* in_sizes, int n_in,
                              void* d_out, int out_size, void* d_ws, size_t ws_size,
                              hipStream_t stream) {
  const float* inputs  = (const float*)d_in[0];  // [B, T, FEAT]
  const float* kernelW = (const float*)d_in[1];  // [FEAT, 4U]
  const float* recW    = (const float*)d_in[2];  // [UNITS, 4U]
  const float* bias    = (const float*)d_in[3];  // [4U]
  const float* dw      = (const float*)d_in[4];  // [UNITS, FEAT]
  const float* db      = (const float*)d_in[5];  // [FEAT]
  float* out = (float*)d_out;                    // [B, OUT_STEPS, 128]

  float* h = (float*)d_ws;                         // [B, UNITS]
  float* c = h + (size_t)BATCH * UNITS;            // [B, UNITS]
  float* Z = c + (size_t)BATCH * UNITS;            // [B, 4U]
  float* y = Z + (size_t)BATCH * N4;               // [B, FEAT]

  hipMemsetAsync(h, 0, sizeof(float) * BATCH * UNITS, stream);
  hipMemsetAsync(c, 0, sizeof(float) * BATCH * UNITS, stream);

  dim3 ggrid(BATCH / BM, N4 / BN);
  const int gate_blocks = (BATCH * UNITS) / 256;

  for (int t = 0; t < TSEQ; ++t) {
    gemm_z_kernel<<<ggrid, 256, 0, stream>>>(inputs + (size_t)t * FEAT, TSEQ * FEAT,
                                             h, kernelW, recW, Z);
    gates_kernel<<<gate_blocks, 256, 0, stream>>>(Z, bias, h, c);
  }
  dense_kernel<<<BATCH / 2, 256, 0, stream>>>(h, dw, db, y, out, 0);
  for (int s = 1; s < OUT_STEPS; ++s) {
    gemm_z_kernel<<<ggrid, 256, 0, stream>>>(y, FEAT, h, kernelW, recW, Z);
    gates_kernel<<<gate_blocks, 256, 0, stream>>>(Z, bias, h, c);
    dense_kernel<<<BATCH / 2, 256, 0, stream>>>(h, dw, db, y, out, s);
  }
}

// Round 2
// 3896.448 us; speedup vs baseline: 5.2550x; 5.2550x over previous
//
#include <hip/hip_runtime.h>
#include <math.h>

#define UNITS 1024
#define FEAT 128
#define TSEQ 48
#define BATCH 2048
#define OUT_STEPS 24
#define KTOT 1152            // FEAT + UNITS
#define N4 4096

typedef unsigned short ushort;
typedef __attribute__((ext_vector_type(8))) short bf16x8;
typedef __attribute__((ext_vector_type(4))) float f32x4;

__device__ __forceinline__ ushort f2bf(float f) {
  unsigned u = __float_as_uint(f);
  unsigned r = (u + 0x7FFF + ((u >> 16) & 1)) >> 16;
  return (ushort)r;
}
__device__ __forceinline__ float sigm(float x) { return 1.0f / (1.0f + __expf(-x)); }
__device__ __forceinline__ float tanh_f(float x) { return 1.0f - 2.0f / (1.0f + __expf(2.0f * x)); }

__device__ __forceinline__ void gload_lds16(const void* g, void* l) {
  __builtin_amdgcn_global_load_lds(
      (const __attribute__((address_space(1))) unsigned int*)g,
      (__attribute__((address_space(3))) unsigned int*)l, 16, 0, 0);
}

// ---------------- prep kernels (run once per launch) ----------------

// inputs [B][T][F] fp32 -> Xb [T][B][F] bf16
__global__ __launch_bounds__(256)
void convert_inputs_kernel(const float* __restrict__ in, ushort* __restrict__ Xb) {
  const int o4 = (blockIdx.x * 256 + threadIdx.x) * 4;  // output elem index (x4)
  const int t = o4 >> 18;             // / (2048*128)
  const int b = (o4 >> 7) & 2047;
  const int f = o4 & 127;
  const float4 v = *reinterpret_cast<const float4*>(&in[(size_t)(b * TSEQ + t) * FEAT + f]);
  union { ushort u[4]; unsigned long long ll; } w;
  w.u[0] = f2bf(v.x); w.u[1] = f2bf(v.y); w.u[2] = f2bf(v.z); w.u[3] = f2bf(v.w);
  *reinterpret_cast<unsigned long long*>(&Xb[o4]) = w.ll;
}

// kernel [128][4096] + recurrent [1024][4096] fp32 -> Wp [4096][1152] bf16, transposed +
// column-permuted: physical col' = (ugrp)*64 + gate*16 + u16, unit = ugrp*16+u16,
// source col = gate*1024 + unit.
__global__ __launch_bounds__(256)
void prep_w_kernel(const float* __restrict__ kW, const float* __restrict__ rW,
                   ushort* __restrict__ Wp) {
  __shared__ ushort tile[32][65];
  const int t = threadIdx.x;
  const int k0 = blockIdx.x * 32;
  const int n0 = blockIdx.y * 64;
#pragma unroll
  for (int p = 0; p < 8; ++p) {
    const int li = p * 256 + t;
    const int nn = li & 63, kk = li >> 6;
    const int np = n0 + nn;
    const int u16 = np & 15, gg = (np >> 4) & 3, ugrp = np >> 6;
    const int nsrc = gg * 1024 + ugrp * 16 + u16;
    const int k = k0 + kk;
    const float v = (k < FEAT) ? kW[(size_t)k * N4 + nsrc] : rW[(size_t)(k - FEAT) * N4 + nsrc];
    tile[kk][nn] = f2bf(v);
  }
  __syncthreads();
#pragma unroll
  for (int p = 0; p < 8; ++p) {
    const int li = p * 256 + t;
    const int kk = li & 31, nn = li >> 5;
    Wp[(size_t)(n0 + nn) * KTOT + k0 + kk] = tile[kk][nn];
  }
}

// dense_w [1024][128] fp32 -> Wdt [128][1024] bf16 (transposed)
__global__ __launch_bounds__(256)
void prep_wd_kernel(const float* __restrict__ dw, ushort* __restrict__ Wdt) {
  const int o = blockIdx.x * 256 + threadIdx.x;  // 0..131071
  const int n = o >> 10, k = o & 1023;
  Wdt[o] = f2bf(dw[(size_t)k * FEAT + n]);
}

// ---------------- fused LSTM step: Z = [X|H] @ Wp^T, gates, state update ----------------
// grid (16, 32): blockIdx.x -> bm (128 rows), blockIdx.y -> bn (128 permuted cols = 32 units)
__global__ __launch_bounds__(256)
void lstm_step_kernel(const ushort* __restrict__ Xc,   // [B][128] bf16
                      const ushort* __restrict__ Hin,  // [B][1024] bf16
                      const ushort* __restrict__ Wp,   // [4096][1152] bf16
                      const float* __restrict__ bias,  // [4096] fp32, orig order
                      float* __restrict__ C,           // [B][1024] fp32
                      ushort* __restrict__ Hout) {     // [B][1024] bf16
  __shared__ alignas(16) ushort sA[128 * 32];
  __shared__ alignas(16) ushort sB[128 * 32];

  const int tid = threadIdx.x;
  const int wid = tid >> 6;
  const int l = tid & 63;
  const int bm = blockIdx.x * 128;
  const int bn = blockIdx.y * 128;
  const int wr = wid >> 1, wc = wid & 1;

  // staging lane geometry: 16 rows x 4 slots per 1KB chunk
  const int rloc = l >> 2;       // 0..15
  const int slot = l & 3;        // physical 16B slot
  const int gsw = slot ^ ((rloc >> 1) & 3);  // logical k-group stored at this slot
  const int l15 = l & 15;
  const int kg = l >> 4;         // k-group for ds_read

  f32x4 acc[4][4] = {};

  for (int k0 = 0; k0 < KTOT; k0 += 32) {
    // ---- stage A (waves 0-1) / B (waves 2-3), 4 chunks of 1KB each ----
    if (wid < 2) {
      const ushort* abase; int astride, aoff;
      if (k0 < FEAT) { abase = Xc; astride = FEAT; aoff = k0; }
      else           { abase = Hin; astride = UNITS; aoff = k0 - FEAT; }
#pragma unroll
      for (int q = 0; q < 4; ++q) {
        const int ct = wid * 4 + q;              // 0..7
        const int r = ct * 16 + rloc;            // tile row
        const ushort* src = abase + (size_t)(bm + r) * astride + aoff + gsw * 8;
        gload_lds16(src, &sA[ct * 512]);
      }
    } else {
#pragma unroll
      for (int q = 0; q < 4; ++q) {
        const int ct = (wid - 2) * 4 + q;        // 0..7
        const int r = ct * 16 + rloc;
        const ushort* src = Wp + (size_t)(bn + r) * KTOT + k0 + gsw * 8;
        gload_lds16(src, &sB[ct * 512]);
      }
    }
    __syncthreads();

    // ---- fragments + MFMA ----
    bf16x8 av[4], bv[4];
#pragma unroll
    for (int m = 0; m < 4; ++m) {
      const int r = wr * 64 + m * 16 + l15;
      const int sph = kg ^ ((r >> 1) & 3);
      av[m] = *reinterpret_cast<const bf16x8*>(&sA[r * 32 + sph * 8]);
    }
#pragma unroll
    for (int n = 0; n < 4; ++n) {
      const int r = wc * 64 + n * 16 + l15;
      const int sph = kg ^ ((r >> 1) & 3);
      bv[n] = *reinterpret_cast<const bf16x8*>(&sB[r * 32 + sph * 8]);
    }
#pragma unroll
    for (int m = 0; m < 4; ++m)
#pragma unroll
      for (int n = 0; n < 4; ++n)
        acc[m][n] = __builtin_amdgcn_mfma_f32_16x16x32_bf16(av[m], bv[n], acc[m][n], 0, 0, 0);
    __syncthreads();
  }

  // ---- epilogue: gates + state update ----
  // acc[m][g]: gate g of unit = (by*2+wc)*16 + l15, rows bm + wr*64 + m*16 + (l>>4)*4 + j
  const int unit = (blockIdx.y * 2 + wc) * 16 + l15;
  const float bi = bias[unit];
  const float bf_ = bias[1024 + unit];
  const float bg = bias[2048 + unit];
  const float bo = bias[3072 + unit];

#pragma unroll
  for (int m = 0; m < 4; ++m) {
    const int rowb = bm + wr * 64 + m * 16 + (l >> 4) * 4;
#pragma unroll
    for (int j = 0; j < 4; ++j) {
      const size_t a = (size_t)(rowb + j) * UNITS + unit;
      const float i_ = sigm(acc[m][0][j] + bi);
      const float f_ = sigm(acc[m][1][j] + bf_);
      const float g_ = tanh_f(acc[m][2][j] + bg);
      const float o_ = sigm(acc[m][3][j] + bo);
      const float cn = f_ * C[a] + i_ * g_;
      C[a] = cn;
      Hout[a] = f2bf(o_ * tanh_f(cn));
    }
  }
}

// ---------------- dense: y = h @ dense_w + b; writes fp32 out + bf16 feedback ----------------
// grid 128 blocks x 1 wave; block handles 16 rows x 128 cols, K=1024
__global__ __launch_bounds__(64)
void dense_kernel(const ushort* __restrict__ Hb, const ushort* __restrict__ Wdt,
                  const float* __restrict__ db, ushort* __restrict__ Yb,
                  float* __restrict__ out, int step) {
  const int l = threadIdx.x;
  const int m0 = blockIdx.x * 16;
  const int l15 = l & 15;
  const int kg = l >> 4;

  f32x4 acc[8] = {};
#pragma unroll 2
  for (int kk = 0; kk < 32; ++kk) {
    const bf16x8 a = *reinterpret_cast<const bf16x8*>(
        &Hb[(size_t)(m0 + l15) * UNITS + kk * 32 + kg * 8]);
#pragma unroll
    for (int n = 0; n < 8; ++n) {
      const bf16x8 b = *reinterpret_cast<const bf16x8*>(
          &Wdt[(size_t)(n * 16 + l15) * UNITS + kk * 32 + kg * 8]);
      acc[n] = __builtin_amdgcn_mfma_f32_16x16x32_bf16(a, b, acc[n], 0, 0, 0);
    }
  }
#pragma unroll
  for (int n = 0; n < 8; ++n) {
    const int col = n * 16 + l15;
    const float bb = db[col];
#pragma unroll
    for (int j = 0; j < 4; ++j) {
      const int row = m0 + kg * 4 + j;
      const float v = acc[n][j] + bb;
      out[((size_t)row * OUT_STEPS + step) * FEAT + col] = v;
      Yb[(size_t)row * FEAT + col] = f2bf(v);
    }
  }
}

// ---------------- launch ----------------
extern "C" void kernel_launch(void* const* d_in, const int* in_sizes, int n_in,
                              void* d_out, int out_size, void* d_ws, size_t ws_size,
                              hipStream_t stream) {
  const float* inputs  = (const float*)d_in[0];
  const float* kernelW = (const float*)d_in[1];
  const float* recW    = (const float*)d_in[2];
  const float* bias    = (const float*)d_in[3];
  const float* dw      = (const float*)d_in[4];
  const float* db      = (const float*)d_in[5];
  float* out = (float*)d_out;

  char* ws = (char*)d_ws;
  float* C    = (float*)ws;                                   // 8,388,608 B
  ushort* Xb  = (ushort*)(ws + 8388608);                      // 25,165,824 B
  ushort* Hb0 = (ushort*)(ws + 8388608 + 25165824);           // 4,194,304 B
  ushort* Hb1 = (ushort*)(ws + 8388608 + 25165824 + 4194304); // 4,194,304 B
  ushort* Wp  = (ushort*)(ws + 8388608 + 25165824 + 8388608); // 9,437,184 B
  ushort* Wdt = (ushort*)(ws + 8388608 + 25165824 + 8388608 + 9437184);   // 262,144 B
  ushort* Yb  = (ushort*)(ws + 8388608 + 25165824 + 8388608 + 9437184 + 262144); // 524,288 B
  ushort* Hb[2] = {Hb0, Hb1};

  convert_inputs_kernel<<<TSEQ * BATCH * FEAT / 1024, 256, 0, stream>>>(inputs, Xb);
  prep_w_kernel<<<dim3(KTOT / 32, N4 / 64), 256, 0, stream>>>(kernelW, recW, Wp);
  prep_wd_kernel<<<FEAT * UNITS / 256, 256, 0, stream>>>(dw, Wdt);
  hipMemsetAsync(C, 0, 8388608, stream);
  hipMemsetAsync(Hb0, 0, 4194304, stream);

  dim3 sgrid(BATCH / 128, N4 / 128);
  int cur = 0;
  for (int t = 0; t < TSEQ; ++t) {
    lstm_step_kernel<<<sgrid, 256, 0, stream>>>(Xb + (size_t)t * BATCH * FEAT,
                                                Hb[cur], Wp, bias, C, Hb[cur ^ 1]);
    cur ^= 1;
  }
  dense_kernel<<<BATCH / 16, 64, 0, stream>>>(Hb[cur], Wdt, db, Yb, out, 0);
  for (int s = 1; s < OUT_STEPS; ++s) {
    lstm_step_kernel<<<sgrid, 256, 0, stream>>>(Yb, Hb[cur], Wp, bias, C, Hb[cur ^ 1]);
    cur ^= 1;
    dense_kernel<<<BATCH / 16, 64, 0, stream>>>(Hb[cur], Wdt, db, Yb, out, s);
  }
}

// Round 3
// 2691.937 us; speedup vs baseline: 7.6063x; 1.4475x over previous
//
#include <hip/hip_runtime.h>
#include <math.h>

#define UNITS 1024
#define FEAT 128
#define TSEQ 48
#define BATCH 2048
#define OUT_STEPS 24
#define KTOT 1152            // FEAT + UNITS
#define N4 4096

typedef unsigned short ushort;
typedef __attribute__((ext_vector_type(8))) short bf16x8;
typedef __attribute__((ext_vector_type(4))) float f32x4;

__device__ __forceinline__ ushort f2bf(float f) {
  unsigned u = __float_as_uint(f);
  unsigned r = (u + 0x7FFF + ((u >> 16) & 1)) >> 16;
  return (ushort)r;
}
__device__ __forceinline__ float sigm(float x) { return 1.0f / (1.0f + __expf(-x)); }
__device__ __forceinline__ float tanh_f(float x) { return 1.0f - 2.0f / (1.0f + __expf(2.0f * x)); }

__device__ __forceinline__ void gload_lds16(const void* g, void* l) {
  __builtin_amdgcn_global_load_lds(
      (const __attribute__((address_space(1))) unsigned int*)g,
      (__attribute__((address_space(3))) unsigned int*)l, 16, 0, 0);
}

// ---------------- prep kernels ----------------

// inputs [B][T][F] fp32 -> Xb [T][B][F] bf16
__global__ __launch_bounds__(256)
void convert_inputs_kernel(const float* __restrict__ in, ushort* __restrict__ Xb) {
  const int o4 = (blockIdx.x * 256 + threadIdx.x) * 4;
  const int t = o4 >> 18;
  const int b = (o4 >> 7) & 2047;
  const int f = o4 & 127;
  const float4 v = *reinterpret_cast<const float4*>(&in[(size_t)(b * TSEQ + t) * FEAT + f]);
  union { ushort u[4]; unsigned long long ll; } w;
  w.u[0] = f2bf(v.x); w.u[1] = f2bf(v.y); w.u[2] = f2bf(v.z); w.u[3] = f2bf(v.w);
  *reinterpret_cast<unsigned long long*>(&Xb[o4]) = w.ll;
}

// kernel [128][4096] + recurrent [1024][4096] fp32 -> Wp [4096][1152] bf16,
// transposed + gate-permuted: physical col' = ugrp*64 + gate*16 + u16.
__global__ __launch_bounds__(256)
void prep_w_kernel(const float* __restrict__ kW, const float* __restrict__ rW,
                   ushort* __restrict__ Wp) {
  __shared__ ushort tile[32][65];
  const int t = threadIdx.x;
  const int k0 = blockIdx.x * 32;
  const int n0 = blockIdx.y * 64;
#pragma unroll
  for (int p = 0; p < 8; ++p) {
    const int li = p * 256 + t;
    const int nn = li & 63, kk = li >> 6;
    const int np = n0 + nn;
    const int u16 = np & 15, gg = (np >> 4) & 3, ugrp = np >> 6;
    const int nsrc = gg * 1024 + ugrp * 16 + u16;
    const int k = k0 + kk;
    const float v = (k < FEAT) ? kW[(size_t)k * N4 + nsrc] : rW[(size_t)(k - FEAT) * N4 + nsrc];
    tile[kk][nn] = f2bf(v);
  }
  __syncthreads();
#pragma unroll
  for (int p = 0; p < 8; ++p) {
    const int li = p * 256 + t;
    const int kk = li & 31, nn = li >> 5;
    Wp[(size_t)(n0 + nn) * KTOT + k0 + kk] = tile[kk][nn];
  }
}

// dense_w [1024][128] fp32 -> Wdt [128][1024] bf16 (transposed)
__global__ __launch_bounds__(256)
void prep_wd_kernel(const float* __restrict__ dw, ushort* __restrict__ Wdt) {
  const int o = blockIdx.x * 256 + threadIdx.x;
  const int n = o >> 10, k = o & 1023;
  Wdt[o] = f2bf(dw[(size_t)k * FEAT + n]);
}

// b2[n] = bias[n] + sum_f db[f] * W[f][n]   (original gate order)
__global__ __launch_bounds__(256)
void prep_b2_kernel(const float* __restrict__ bias, const float* __restrict__ db,
                    const float* __restrict__ W, float* __restrict__ b2) {
  const int n = blockIdx.x * 256 + threadIdx.x;
  float s = bias[n];
#pragma unroll 8
  for (int f = 0; f < FEAT; ++f) s += db[f] * W[(size_t)f * N4 + n];
  b2[n] = s;
}

// U' = Wd@W + U  -> Wp2 [4096][1024] bf16, transposed + gate-permuted.
// grid (64 n'-tiles, 16 k-tiles), block 256.
__global__ __launch_bounds__(256)
void prep_u_kernel(const float* __restrict__ dw,   // [1024][128]
                   const float* __restrict__ W,    // [128][4096]
                   const float* __restrict__ rW,   // [1024][4096]
                   ushort* __restrict__ Wp2) {
  __shared__ float sWd[64][132];   // [k_local][f]
  __shared__ float sW[128][68];    // [f][n'_local]
  const int tid = threadIdx.x;
  const int ugrp = blockIdx.x;          // n0 = ugrp*64
  const int k0 = blockIdx.y * 64;
  const int n0 = ugrp * 64;

#pragma unroll
  for (int p = 0; p < 8; ++p) {
    const int li = p * 256 + tid;       // float4 slots
    const int kk = li >> 5, f4 = (li & 31) * 4;
    *reinterpret_cast<float4*>(&sWd[kk][f4]) =
        *reinterpret_cast<const float4*>(&dw[(size_t)(k0 + kk) * FEAT + f4]);
  }
#pragma unroll
  for (int p = 0; p < 32; ++p) {
    const int li = p * 256 + tid;
    const int f = li >> 6, nn = li & 63;
    const int u16 = nn & 15, gg = (nn >> 4) & 3;
    const int nsrc = gg * 1024 + ugrp * 16 + u16;
    sW[f][nn] = W[(size_t)f * N4 + nsrc];
  }
  __syncthreads();

  const int tx = tid & 15;   // k sub (4)
  const int ty = tid >> 4;   // n' sub (4)
  float acc[4][4] = {};      // [i=n'][j=k]
  for (int f = 0; f < 128; ++f) {
    float a[4], b[4];
#pragma unroll
    for (int j = 0; j < 4; ++j) a[j] = sWd[tx * 4 + j][f];
#pragma unroll
    for (int i = 0; i < 4; ++i) b[i] = sW[f][ty * 4 + i];
#pragma unroll
    for (int i = 0; i < 4; ++i)
#pragma unroll
      for (int j = 0; j < 4; ++j) acc[i][j] += a[j] * b[i];
  }

#pragma unroll
  for (int i = 0; i < 4; ++i) {
    const int np = n0 + ty * 4 + i;
    const int u16 = np & 15, gg = (np >> 4) & 3;
    const int nsrc = gg * 1024 + ugrp * 16 + u16;
#pragma unroll
    for (int j = 0; j < 4; ++j) {
      const int k = k0 + tx * 4 + j;
      const float v = rW[(size_t)k * N4 + nsrc] + acc[i][j];
      Wp2[(size_t)np * UNITS + k] = f2bf(v);
    }
  }
}

// ---------------- fused LSTM step ----------------
// KT = K length (1152 with X, 1024 decode). grid 512 blocks 1D (XCD-swizzled).
template<int KT, bool HASX>
__global__ __launch_bounds__(256)
void lstm_step_kernel(const ushort* __restrict__ Xc,   // [B][128] bf16 (warmup only)
                      const ushort* __restrict__ Hin,  // [B][1024] bf16
                      const ushort* __restrict__ Wp,   // [4096][KT] bf16
                      const float* __restrict__ bias,  // [4096] fp32, orig gate order
                      float* __restrict__ C,           // [B][1024] fp32
                      ushort* __restrict__ Hout) {     // [B][1024] bf16
  __shared__ alignas(16) ushort sA[128 * 32];
  __shared__ alignas(16) ushort sB[128 * 32];

  const int bid = blockIdx.x;
  const int wg = (bid & 7) * 64 + (bid >> 3);   // bijective XCD chunk swizzle (512 % 8 == 0)
  const int bx = wg & 15, by = wg >> 4;
  const int bm = bx * 128;
  const int bn = by * 128;

  const int tid = threadIdx.x;
  const int wid = tid >> 6;
  const int l = tid & 63;
  const int wr = wid >> 1, wc = wid & 1;

  const int rloc = l >> 2;
  const int slot = l & 3;
  const int gsw = slot ^ ((rloc >> 1) & 3);
  const int l15 = l & 15;
  const int kg = l >> 4;

  f32x4 acc[4][4] = {};

  for (int k0 = 0; k0 < KT; k0 += 32) {
    if (wid < 2) {
      const ushort* abase; int astride, aoff;
      if (HASX && k0 < FEAT) { abase = Xc; astride = FEAT; aoff = k0; }
      else { abase = Hin; astride = UNITS; aoff = k0 - (HASX ? FEAT : 0); }
#pragma unroll
      for (int q = 0; q < 4; ++q) {
        const int ct = wid * 4 + q;
        const int r = ct * 16 + rloc;
        const ushort* src = abase + (size_t)(bm + r) * astride + aoff + gsw * 8;
        gload_lds16(src, &sA[ct * 512]);
      }
    } else {
#pragma unroll
      for (int q = 0; q < 4; ++q) {
        const int ct = (wid - 2) * 4 + q;
        const int r = ct * 16 + rloc;
        const ushort* src = Wp + (size_t)(bn + r) * KT + k0 + gsw * 8;
        gload_lds16(src, &sB[ct * 512]);
      }
    }
    __syncthreads();

    bf16x8 av[4], bv[4];
#pragma unroll
    for (int m = 0; m < 4; ++m) {
      const int r = wr * 64 + m * 16 + l15;
      const int sph = kg ^ ((r >> 1) & 3);
      av[m] = *reinterpret_cast<const bf16x8*>(&sA[r * 32 + sph * 8]);
    }
#pragma unroll
    for (int n = 0; n < 4; ++n) {
      const int r = wc * 64 + n * 16 + l15;
      const int sph = kg ^ ((r >> 1) & 3);
      bv[n] = *reinterpret_cast<const bf16x8*>(&sB[r * 32 + sph * 8]);
    }
#pragma unroll
    for (int m = 0; m < 4; ++m)
#pragma unroll
      for (int n = 0; n < 4; ++n)
        acc[m][n] = __builtin_amdgcn_mfma_f32_16x16x32_bf16(av[m], bv[n], acc[m][n], 0, 0, 0);
    __syncthreads();
  }

  const int unit = (by * 2 + wc) * 16 + l15;
  const float bi = bias[unit];
  const float bf_ = bias[1024 + unit];
  const float bg = bias[2048 + unit];
  const float bo = bias[3072 + unit];

#pragma unroll
  for (int m = 0; m < 4; ++m) {
    const int rowb = bm + wr * 64 + m * 16 + (l >> 4) * 4;
#pragma unroll
    for (int j = 0; j < 4; ++j) {
      const size_t a = (size_t)(rowb + j) * UNITS + unit;
      const float i_ = sigm(acc[m][0][j] + bi);
      const float f_ = sigm(acc[m][1][j] + bf_);
      const float g_ = tanh_f(acc[m][2][j] + bg);
      const float o_ = sigm(acc[m][3][j] + bo);
      const float cn = f_ * C[a] + i_ * g_;
      C[a] = cn;
      Hout[a] = f2bf(o_ * tanh_f(cn));
    }
  }
}

// ---------------- dense (output only): out[:,step,:] = h @ Wd + db ----------------
// 128 blocks x 4 waves; K split across waves + LDS reduction.
__global__ __launch_bounds__(256)
void dense_kernel(const ushort* __restrict__ Hb, const ushort* __restrict__ Wdt,
                  const float* __restrict__ db, float* __restrict__ out, int step) {
  __shared__ f32x4 part[4][8][64];
  const int tid = threadIdx.x;
  const int w = tid >> 6, l = tid & 63;
  const int m0 = blockIdx.x * 16;
  const int l15 = l & 15, kg = l >> 4;

  f32x4 acc[8] = {};
  const int kbase = w * 256;
#pragma unroll
  for (int kk = 0; kk < 8; ++kk) {
    const int kofs = kbase + kk * 32 + kg * 8;
    const bf16x8 a = *reinterpret_cast<const bf16x8*>(&Hb[(size_t)(m0 + l15) * UNITS + kofs]);
#pragma unroll
    for (int n = 0; n < 8; ++n) {
      const bf16x8 b = *reinterpret_cast<const bf16x8*>(&Wdt[(size_t)(n * 16 + l15) * UNITS + kofs]);
      acc[n] = __builtin_amdgcn_mfma_f32_16x16x32_bf16(a, b, acc[n], 0, 0, 0);
    }
  }
#pragma unroll
  for (int n = 0; n < 8; ++n) part[w][n][l] = acc[n];
  __syncthreads();

#pragma unroll
  for (int t2 = 0; t2 < 2; ++t2) {
    const int n = w * 2 + t2;
    f32x4 r = part[0][n][l];
#pragma unroll
    for (int p = 1; p < 4; ++p) r += part[p][n][l];
    const int col = n * 16 + l15;
    const float bb = db[col];
#pragma unroll
    for (int j = 0; j < 4; ++j) {
      const int row = m0 + kg * 4 + j;
      out[((size_t)row * OUT_STEPS + step) * FEAT + col] = r[j] + bb;
    }
  }
}

// ---------------- launch ----------------
extern "C" void kernel_launch(void* const* d_in, const int* in_sizes, int n_in,
                              void* d_out, int out_size, void* d_ws, size_t ws_size,
                              hipStream_t stream) {
  const float* inputs  = (const float*)d_in[0];
  const float* kernelW = (const float*)d_in[1];
  const float* recW    = (const float*)d_in[2];
  const float* bias    = (const float*)d_in[3];
  const float* dw      = (const float*)d_in[4];
  const float* db      = (const float*)d_in[5];
  float* out = (float*)d_out;

  char* ws = (char*)d_ws;
  float* C    = (float*)ws;                                    // 8 MB
  ushort* Xb  = (ushort*)(ws + 8388608);                       // 24 MB (warmup only)
  ushort* Wp2 = Xb;                                            // 8 MB, aliases Xb (used after warmup)
  ushort* Hb0 = (ushort*)(ws + 8388608 + 25165824);            // 4 MB
  ushort* Hb1 = (ushort*)(ws + 8388608 + 25165824 + 4194304);  // 4 MB
  ushort* Wp  = (ushort*)(ws + 8388608 + 25165824 + 8388608);  // 9 MB
  ushort* Wdt = (ushort*)(ws + 8388608 + 25165824 + 8388608 + 9437184);           // 256 KB
  float*  b2  = (float*)(ws + 8388608 + 25165824 + 8388608 + 9437184 + 262144);   // 16 KB
  ushort* Hb[2] = {Hb0, Hb1};

  convert_inputs_kernel<<<TSEQ * BATCH * FEAT / 1024, 256, 0, stream>>>(inputs, Xb);
  prep_w_kernel<<<dim3(KTOT / 32, N4 / 64), 256, 0, stream>>>(kernelW, recW, Wp);
  prep_wd_kernel<<<FEAT * UNITS / 256, 256, 0, stream>>>(dw, Wdt);
  prep_b2_kernel<<<N4 / 256, 256, 0, stream>>>(bias, db, kernelW, b2);
  hipMemsetAsync(C, 0, 8388608, stream);
  hipMemsetAsync(Hb0, 0, 4194304, stream);

  int cur = 0;
  for (int t = 0; t < TSEQ; ++t) {
    lstm_step_kernel<KTOT, true><<<512, 256, 0, stream>>>(
        Xb + (size_t)t * BATCH * FEAT, Hb[cur], Wp, bias, C, Hb[cur ^ 1]);
    cur ^= 1;
  }
  // Wp2 aliases Xb — build it only after the warmup has consumed Xb.
  prep_u_kernel<<<dim3(64, 16), 256, 0, stream>>>(dw, kernelW, recW, Wp2);

  dense_kernel<<<BATCH / 16, 256, 0, stream>>>(Hb[cur], Wdt, db, out, 0);
  for (int s = 1; s < OUT_STEPS; ++s) {
    lstm_step_kernel<UNITS, false><<<512, 256, 0, stream>>>(
        nullptr, Hb[cur], Wp2, b2, C, Hb[cur ^ 1]);
    cur ^= 1;
    dense_kernel<<<BATCH / 16, 256, 0, stream>>>(Hb[cur], Wdt, db, out, s);
  }
}

// Round 4
// 2227.283 us; speedup vs baseline: 9.1932x; 1.2086x over previous
//
#include <hip/hip_runtime.h>
#include <math.h>

#define UNITS 1024
#define FEAT 128
#define TSEQ 48
#define BATCH 2048
#define OUT_STEPS 24
#define KTOT 1152            // FEAT + UNITS
#define N4 4096

typedef unsigned short ushort;
typedef __attribute__((ext_vector_type(8))) short bf16x8;
typedef __attribute__((ext_vector_type(4))) float f32x4;

__device__ __forceinline__ ushort f2bf(float f) {
  unsigned u = __float_as_uint(f);
  unsigned r = (u + 0x7FFF + ((u >> 16) & 1)) >> 16;
  return (ushort)r;
}
__device__ __forceinline__ float sigm(float x) { return 1.0f / (1.0f + __expf(-x)); }
__device__ __forceinline__ float tanh_f(float x) { return 1.0f - 2.0f / (1.0f + __expf(2.0f * x)); }

__device__ __forceinline__ void gload_lds16(const void* g, void* l) {
  __builtin_amdgcn_global_load_lds(
      (const __attribute__((address_space(1))) unsigned int*)g,
      (__attribute__((address_space(3))) unsigned int*)l, 16, 0, 0);
}

// ---------------- prep kernels ----------------

// inputs [B][T][F] fp32 -> Xb [T][B][F] bf16
__global__ __launch_bounds__(256)
void convert_inputs_kernel(const float* __restrict__ in, ushort* __restrict__ Xb) {
  const int o4 = (blockIdx.x * 256 + threadIdx.x) * 4;
  const int t = o4 >> 18;
  const int b = (o4 >> 7) & 2047;
  const int f = o4 & 127;
  const float4 v = *reinterpret_cast<const float4*>(&in[(size_t)(b * TSEQ + t) * FEAT + f]);
  union { ushort u[4]; unsigned long long ll; } w;
  w.u[0] = f2bf(v.x); w.u[1] = f2bf(v.y); w.u[2] = f2bf(v.z); w.u[3] = f2bf(v.w);
  *reinterpret_cast<unsigned long long*>(&Xb[o4]) = w.ll;
}

// kernel [128][4096] + recurrent [1024][4096] fp32 -> Wp [4096][1152] bf16,
// transposed + gate-permuted: physical col' = ugrp*64 + gate*16 + u16.
__global__ __launch_bounds__(256)
void prep_w_kernel(const float* __restrict__ kW, const float* __restrict__ rW,
                   ushort* __restrict__ Wp) {
  __shared__ ushort tile[32][65];
  const int t = threadIdx.x;
  const int k0 = blockIdx.x * 32;
  const int n0 = blockIdx.y * 64;
#pragma unroll
  for (int p = 0; p < 8; ++p) {
    const int li = p * 256 + t;
    const int nn = li & 63, kk = li >> 6;
    const int np = n0 + nn;
    const int u16 = np & 15, gg = (np >> 4) & 3, ugrp = np >> 6;
    const int nsrc = gg * 1024 + ugrp * 16 + u16;
    const int k = k0 + kk;
    const float v = (k < FEAT) ? kW[(size_t)k * N4 + nsrc] : rW[(size_t)(k - FEAT) * N4 + nsrc];
    tile[kk][nn] = f2bf(v);
  }
  __syncthreads();
#pragma unroll
  for (int p = 0; p < 8; ++p) {
    const int li = p * 256 + t;
    const int kk = li & 31, nn = li >> 5;
    Wp[(size_t)(n0 + nn) * KTOT + k0 + kk] = tile[kk][nn];
  }
}

// dense_w [1024][128] fp32 -> Wdt [128][1024] bf16 (transposed)
__global__ __launch_bounds__(256)
void prep_wd_kernel(const float* __restrict__ dw, ushort* __restrict__ Wdt) {
  const int o = blockIdx.x * 256 + threadIdx.x;
  const int n = o >> 10, k = o & 1023;
  Wdt[o] = f2bf(dw[(size_t)k * FEAT + n]);
}

// b2[n] = bias[n] + sum_f db[f] * W[f][n]   (original gate order)
__global__ __launch_bounds__(256)
void prep_b2_kernel(const float* __restrict__ bias, const float* __restrict__ db,
                    const float* __restrict__ W, float* __restrict__ b2) {
  const int n = blockIdx.x * 256 + threadIdx.x;
  float s = bias[n];
#pragma unroll 8
  for (int f = 0; f < FEAT; ++f) s += db[f] * W[(size_t)f * N4 + n];
  b2[n] = s;
}

// U' = Wd@W + U  -> Wp2 [4096][1024] bf16, transposed + gate-permuted.
__global__ __launch_bounds__(256)
void prep_u_kernel(const float* __restrict__ dw,   // [1024][128]
                   const float* __restrict__ W,    // [128][4096]
                   const float* __restrict__ rW,   // [1024][4096]
                   ushort* __restrict__ Wp2) {
  __shared__ float sWd[64][132];   // [k_local][f]
  __shared__ float sW[128][68];    // [f][n'_local]
  const int tid = threadIdx.x;
  const int ugrp = blockIdx.x;
  const int k0 = blockIdx.y * 64;
  const int n0 = ugrp * 64;

#pragma unroll
  for (int p = 0; p < 8; ++p) {
    const int li = p * 256 + tid;
    const int kk = li >> 5, f4 = (li & 31) * 4;
    *reinterpret_cast<float4*>(&sWd[kk][f4]) =
        *reinterpret_cast<const float4*>(&dw[(size_t)(k0 + kk) * FEAT + f4]);
  }
#pragma unroll
  for (int p = 0; p < 32; ++p) {
    const int li = p * 256 + tid;
    const int f = li >> 6, nn = li & 63;
    const int u16 = nn & 15, gg = (nn >> 4) & 3;
    const int nsrc = gg * 1024 + ugrp * 16 + u16;
    sW[f][nn] = W[(size_t)f * N4 + nsrc];
  }
  __syncthreads();

  const int tx = tid & 15;
  const int ty = tid >> 4;
  float acc[4][4] = {};
  for (int f = 0; f < 128; ++f) {
    float a[4], b[4];
#pragma unroll
    for (int j = 0; j < 4; ++j) a[j] = sWd[tx * 4 + j][f];
#pragma unroll
    for (int i = 0; i < 4; ++i) b[i] = sW[f][ty * 4 + i];
#pragma unroll
    for (int i = 0; i < 4; ++i)
#pragma unroll
      for (int j = 0; j < 4; ++j) acc[i][j] += a[j] * b[i];
  }

#pragma unroll
  for (int i = 0; i < 4; ++i) {
    const int np = n0 + ty * 4 + i;
    const int u16 = np & 15, gg = (np >> 4) & 3;
    const int nsrc = gg * 1024 + ugrp * 16 + u16;
#pragma unroll
    for (int j = 0; j < 4; ++j) {
      const int k = k0 + tx * 4 + j;
      const float v = rW[(size_t)k * N4 + nsrc] + acc[i][j];
      Wp2[(size_t)np * UNITS + k] = f2bf(v);
    }
  }
}

// ---------------- fused LSTM step: 2-phase schedule, 8 waves ----------------
// 128x128 tile, double-buffered LDS, single barrier per K-iter,
// stage(t+1) issued before compute(t). grid 512 (XCD-swizzled).
template<int KT, bool HASX>
__global__ __launch_bounds__(512, 4)
void lstm_step_kernel(const ushort* __restrict__ Xc,   // [B][128] bf16 (warmup only)
                      const ushort* __restrict__ Hin,  // [B][1024] bf16
                      const ushort* __restrict__ Wp,   // [4096][KT] bf16
                      const float* __restrict__ bias,  // [4096] fp32, orig gate order
                      float* __restrict__ C,           // [B][1024] fp32
                      ushort* __restrict__ Hout) {     // [B][1024] bf16
  __shared__ alignas(16) ushort sA[2][128 * 32];
  __shared__ alignas(16) ushort sB[2][128 * 32];

  const int bid = blockIdx.x;
  const int wg = (bid & 7) * 64 + (bid >> 3);   // bijective XCD chunk swizzle (512%8==0)
  const int bx = wg & 15, by = wg >> 4;
  const int bm = bx * 128;
  const int bn = by * 128;

  const int tid = threadIdx.x;
  const int wid = tid >> 6;
  const int l = tid & 63;
  const int wr = wid >> 1;     // 0..3 -> rows wr*32
  const int wc = wid & 1;      // 0..1 -> cols wc*64

  const int rloc = l >> 2;
  const int slot = l & 3;
  const int gsw = slot ^ ((rloc >> 1) & 3);
  const int l15 = l & 15;
  const int kg = l >> 4;

  f32x4 acc[2][4] = {};

  // Each wave stages 2 of 16 chunks (1 KB each): chunks 0-7 -> sA, 8-15 -> sB.
  auto STAGE = [&](int k0s, int bsel) {
#pragma unroll
    for (int q = 0; q < 2; ++q) {
      const int c = wid * 2 + q;
      if (c < 8) {
        const int r = c * 16 + rloc;
        const ushort* src;
        if (HASX && k0s < FEAT)
          src = Xc + (size_t)(bm + r) * FEAT + k0s + gsw * 8;
        else
          src = Hin + (size_t)(bm + r) * UNITS + (k0s - (HASX ? FEAT : 0)) + gsw * 8;
        gload_lds16(src, &sA[bsel][c * 512]);
      } else {
        const int cb = c - 8;
        const int r = cb * 16 + rloc;
        const ushort* src = Wp + (size_t)(bn + r) * KT + k0s + gsw * 8;
        gload_lds16(src, &sB[bsel][cb * 512]);
      }
    }
  };

  constexpr int NT = KT / 32;
  STAGE(0, 0);
  __syncthreads();
  int cur = 0;
  for (int t = 0; t < NT; ++t) {
    if (t + 1 < NT) STAGE((t + 1) * 32, cur ^ 1);

    bf16x8 av[2], bv[4];
#pragma unroll
    for (int m = 0; m < 2; ++m) {
      const int r = wr * 32 + m * 16 + l15;
      const int sph = kg ^ ((r >> 1) & 3);
      av[m] = *reinterpret_cast<const bf16x8*>(&sA[cur][r * 32 + sph * 8]);
    }
#pragma unroll
    for (int n = 0; n < 4; ++n) {
      const int r = wc * 64 + n * 16 + l15;
      const int sph = kg ^ ((r >> 1) & 3);
      bv[n] = *reinterpret_cast<const bf16x8*>(&sB[cur][r * 32 + sph * 8]);
    }
#pragma unroll
    for (int m = 0; m < 2; ++m)
#pragma unroll
      for (int n = 0; n < 4; ++n)
        acc[m][n] = __builtin_amdgcn_mfma_f32_16x16x32_bf16(av[m], bv[n], acc[m][n], 0, 0, 0);

    __syncthreads();   // drains vmcnt (stage t+1 landed) + syncs LDS reuse
    cur ^= 1;
  }

  // ---- epilogue: gates + state update ----
  const int unit = (by * 2 + wc) * 16 + l15;
  const float bi = bias[unit];
  const float bf_ = bias[1024 + unit];
  const float bg = bias[2048 + unit];
  const float bo = bias[3072 + unit];

#pragma unroll
  for (int m = 0; m < 2; ++m) {
    const int rowb = bm + wr * 32 + m * 16 + kg * 4;
#pragma unroll
    for (int j = 0; j < 4; ++j) {
      const size_t a = (size_t)(rowb + j) * UNITS + unit;
      const float i_ = sigm(acc[m][0][j] + bi);
      const float f_ = sigm(acc[m][1][j] + bf_);
      const float g_ = tanh_f(acc[m][2][j] + bg);
      const float o_ = sigm(acc[m][3][j] + bo);
      const float cn = f_ * C[a] + i_ * g_;
      C[a] = cn;
      Hout[a] = f2bf(o_ * tanh_f(cn));
    }
  }
}

// ---------------- batched dense: out[b][s][f] = Hall[s][b] . Wd[:,f] + db[f] ----------------
// M=49152 (24*2048) rows, N=128, K=1024. BM=64, 4 waves, 2-phase, grid 768.
__global__ __launch_bounds__(256)
void dense_all_kernel(const ushort* __restrict__ Hall,  // [24][2048][1024] bf16
                      const ushort* __restrict__ Wdt,   // [128][1024] bf16
                      const float* __restrict__ db,
                      float* __restrict__ out) {        // [2048][24][128] fp32
  __shared__ alignas(16) ushort sA[2][64 * 32];
  __shared__ alignas(16) ushort sB[2][128 * 32];

  const int bm = blockIdx.x * 64;
  const int tid = threadIdx.x;
  const int wid = tid >> 6;
  const int l = tid & 63;
  const int wr = wid >> 1;   // 0..1 -> rows wr*32
  const int wc = wid & 1;    // cols wc*64

  const int rloc = l >> 2;
  const int slot = l & 3;
  const int gsw = slot ^ ((rloc >> 1) & 3);
  const int l15 = l & 15;
  const int kg = l >> 4;

  f32x4 acc[2][4] = {};

  auto STAGE = [&](int k0s, int bsel) {
#pragma unroll
    for (int q = 0; q < 3; ++q) {
      const int c = wid * 3 + q;   // 0..11: 0-3 sA, 4-11 sB
      if (c < 4) {
        const int r = c * 16 + rloc;
        gload_lds16(Hall + (size_t)(bm + r) * UNITS + k0s + gsw * 8, &sA[bsel][c * 512]);
      } else {
        const int cb = c - 4;
        const int r = cb * 16 + rloc;
        gload_lds16(Wdt + (size_t)r * UNITS + k0s + gsw * 8, &sB[bsel][cb * 512]);
      }
    }
  };

  STAGE(0, 0);
  __syncthreads();
  int cur = 0;
  for (int t = 0; t < 32; ++t) {
    if (t + 1 < 32) STAGE((t + 1) * 32, cur ^ 1);

    bf16x8 av[2], bv[4];
#pragma unroll
    for (int m = 0; m < 2; ++m) {
      const int r = wr * 32 + m * 16 + l15;
      const int sph = kg ^ ((r >> 1) & 3);
      av[m] = *reinterpret_cast<const bf16x8*>(&sA[cur][r * 32 + sph * 8]);
    }
#pragma unroll
    for (int n = 0; n < 4; ++n) {
      const int r = wc * 64 + n * 16 + l15;
      const int sph = kg ^ ((r >> 1) & 3);
      bv[n] = *reinterpret_cast<const bf16x8*>(&sB[cur][r * 32 + sph * 8]);
    }
#pragma unroll
    for (int m = 0; m < 2; ++m)
#pragma unroll
      for (int n = 0; n < 4; ++n)
        acc[m][n] = __builtin_amdgcn_mfma_f32_16x16x32_bf16(av[m], bv[n], acc[m][n], 0, 0, 0);

    __syncthreads();
    cur ^= 1;
  }

#pragma unroll
  for (int n = 0; n < 4; ++n) {
    const int f = wc * 64 + n * 16 + l15;
    const float bb = db[f];
#pragma unroll
    for (int m = 0; m < 2; ++m) {
#pragma unroll
      for (int j = 0; j < 4; ++j) {
        const int r = bm + wr * 32 + m * 16 + kg * 4 + j;
        const int s = r >> 11, b = r & 2047;
        out[((size_t)b * OUT_STEPS + s) * FEAT + f] = acc[m][n][j] + bb;
      }
    }
  }
}

// ---------------- launch ----------------
extern "C" void kernel_launch(void* const* d_in, const int* in_sizes, int n_in,
                              void* d_out, int out_size, void* d_ws, size_t ws_size,
                              hipStream_t stream) {
  const float* inputs  = (const float*)d_in[0];
  const float* kernelW = (const float*)d_in[1];
  const float* recW    = (const float*)d_in[2];
  const float* bias    = (const float*)d_in[3];
  const float* dw      = (const float*)d_in[4];
  const float* db      = (const float*)d_in[5];
  float* out = (float*)d_out;

  char* ws = (char*)d_ws;
  float* C    = (float*)ws;                                    // 8 MB
  ushort* Xb  = (ushort*)(ws + 8388608);                       // 24 MB (warmup only)
  ushort* Wp2 = Xb;                                            // 8 MB, aliases Xb
  ushort* Hb0 = (ushort*)(ws + 33554432);                      // 4 MB
  ushort* Hb1 = (ushort*)(ws + 37748736);                      // 4 MB
  ushort* Wp  = (ushort*)(ws + 41943040);                      // 9 MB
  ushort* Wdt = (ushort*)(ws + 51380224);                      // 256 KB
  float*  b2  = (float*)(ws + 51642368);                       // 16 KB
  ushort* Hall = (ushort*)(ws + 51658752);                     // 96 MB: [24][2048][1024]
  ushort* Hb[2] = {Hb0, Hb1};
  const size_t HSLOT = (size_t)BATCH * UNITS;

  convert_inputs_kernel<<<TSEQ * BATCH * FEAT / 1024, 256, 0, stream>>>(inputs, Xb);
  prep_w_kernel<<<dim3(KTOT / 32, N4 / 64), 256, 0, stream>>>(kernelW, recW, Wp);
  prep_wd_kernel<<<FEAT * UNITS / 256, 256, 0, stream>>>(dw, Wdt);
  prep_b2_kernel<<<N4 / 256, 256, 0, stream>>>(bias, db, kernelW, b2);
  hipMemsetAsync(C, 0, 8388608, stream);
  hipMemsetAsync(Hb0, 0, 4194304, stream);

  int cur = 0;
  for (int t = 0; t < TSEQ; ++t) {
    ushort* hout = (t == TSEQ - 1) ? Hall : Hb[cur ^ 1];
    lstm_step_kernel<KTOT, true><<<512, 512, 0, stream>>>(
        Xb + (size_t)t * BATCH * FEAT, Hb[cur], Wp, bias, C, hout);
    cur ^= 1;
  }
  // Wp2 aliases Xb — build only after warmup consumed Xb.
  prep_u_kernel<<<dim3(64, 16), 256, 0, stream>>>(dw, kernelW, recW, Wp2);

  for (int s = 1; s < OUT_STEPS; ++s) {
    lstm_step_kernel<UNITS, false><<<512, 512, 0, stream>>>(
        nullptr, Hall + (size_t)(s - 1) * HSLOT, Wp2, b2, C, Hall + (size_t)s * HSLOT);
  }
  dense_all_kernel<<<(OUT_STEPS * BATCH) / 64, 256, 0, stream>>>(Hall, Wdt, db, out);
}

// Round 5
// 2003.419 us; speedup vs baseline: 10.2204x; 1.1117x over previous
//
#include <hip/hip_runtime.h>
#include <math.h>

#define UNITS 1024
#define FEAT 128
#define TSEQ 48
#define BATCH 2048
#define OUT_STEPS 24
#define KTOT 1152            // FEAT + UNITS
#define N4 4096

typedef unsigned short ushort;
typedef __attribute__((ext_vector_type(8))) short bf16x8;
typedef __attribute__((ext_vector_type(4))) float f32x4;

__device__ __forceinline__ ushort f2bf(float f) {
  unsigned u = __float_as_uint(f);
  unsigned r = (u + 0x7FFF + ((u >> 16) & 1)) >> 16;
  return (ushort)r;
}
__device__ __forceinline__ float sigm(float x) { return 1.0f / (1.0f + __expf(-x)); }
__device__ __forceinline__ float tanh_f(float x) { return 1.0f - 2.0f / (1.0f + __expf(2.0f * x)); }

__device__ __forceinline__ void gload_lds16(const void* g, void* l) {
  __builtin_amdgcn_global_load_lds(
      (const __attribute__((address_space(1))) unsigned int*)g,
      (__attribute__((address_space(3))) unsigned int*)l, 16, 0, 0);
}

// ---------------- prep kernels ----------------

// inputs [B][T][F] fp32 -> Xb [T][B][F] bf16
__global__ __launch_bounds__(256)
void convert_inputs_kernel(const float* __restrict__ in, ushort* __restrict__ Xb) {
  const int o4 = (blockIdx.x * 256 + threadIdx.x) * 4;
  const int t = o4 >> 18;
  const int b = (o4 >> 7) & 2047;
  const int f = o4 & 127;
  const float4 v = *reinterpret_cast<const float4*>(&in[(size_t)(b * TSEQ + t) * FEAT + f]);
  union { ushort u[4]; unsigned long long ll; } w;
  w.u[0] = f2bf(v.x); w.u[1] = f2bf(v.y); w.u[2] = f2bf(v.z); w.u[3] = f2bf(v.w);
  *reinterpret_cast<unsigned long long*>(&Xb[o4]) = w.ll;
}

// Build WpF: warmup weights in MFMA-fragment order.
// Fragment (cf, kc): 64 lanes x 8 bf16. lane = kgq*16 + u16loc; np = cf*16 + u16loc;
// k = kc*32 + kgq*8 + e. np is the gate-permuted column: np = ugrp*64 + gate*16 + u16,
// source col = gate*1024 + ugrp*16 + u16. Row k<128 -> kernel, else recurrent.
__global__ __launch_bounds__(256)
void prep_wF_kernel(const float* __restrict__ kW, const float* __restrict__ rW,
                    ushort* __restrict__ WpF) {
  const int g = blockIdx.x * 256 + threadIdx.x;   // (cf*36 + kc)*64 + lane
  const int lane = g & 63;
  const int kc = (g >> 6) % 36;
  const int cf = g / 2304;                         // 36*64
  const int np = cf * 16 + (lane & 15);
  const int kbase = kc * 32 + (lane >> 4) * 8;
  const int u16 = np & 15, gg = (np >> 4) & 3, ugrp = np >> 6;
  const int nsrc = gg * 1024 + ugrp * 16 + u16;
  ushort v[8];
#pragma unroll
  for (int e = 0; e < 8; ++e) {
    const int k = kbase + e;
    const float f = (k < FEAT) ? kW[(size_t)k * N4 + nsrc] : rW[(size_t)(k - FEAT) * N4 + nsrc];
    v[e] = f2bf(f);
  }
  *reinterpret_cast<bf16x8*>(&WpF[(size_t)g * 8]) = *reinterpret_cast<bf16x8*>(v);
}

// dense_w [1024][128] fp32 -> Wdt [128][1024] bf16 (transposed)
__global__ __launch_bounds__(256)
void prep_wd_kernel(const float* __restrict__ dw, ushort* __restrict__ Wdt) {
  const int o = blockIdx.x * 256 + threadIdx.x;
  const int n = o >> 10, k = o & 1023;
  Wdt[o] = f2bf(dw[(size_t)k * FEAT + n]);
}

// b2[n] = bias[n] + sum_f db[f] * W[f][n]   (original gate order)
__global__ __launch_bounds__(256)
void prep_b2_kernel(const float* __restrict__ bias, const float* __restrict__ db,
                    const float* __restrict__ W, float* __restrict__ b2) {
  const int n = blockIdx.x * 256 + threadIdx.x;
  float s = bias[n];
#pragma unroll 8
  for (int f = 0; f < FEAT; ++f) s += db[f] * W[(size_t)f * N4 + n];
  b2[n] = s;
}

// U' = Wd@W + U -> Wp2F in fragment order (NK=32).
__global__ __launch_bounds__(256)
void prep_u_kernel(const float* __restrict__ dw,   // [1024][128]
                   const float* __restrict__ W,    // [128][4096]
                   const float* __restrict__ rW,   // [1024][4096]
                   ushort* __restrict__ Wp2F) {
  __shared__ float sWd[64][132];   // [k_local][f]
  __shared__ float sW[128][68];    // [f][n'_local]
  const int tid = threadIdx.x;
  const int ugrp = blockIdx.x;
  const int k0 = blockIdx.y * 64;
  const int n0 = ugrp * 64;

#pragma unroll
  for (int p = 0; p < 8; ++p) {
    const int li = p * 256 + tid;
    const int kk = li >> 5, f4 = (li & 31) * 4;
    *reinterpret_cast<float4*>(&sWd[kk][f4]) =
        *reinterpret_cast<const float4*>(&dw[(size_t)(k0 + kk) * FEAT + f4]);
  }
#pragma unroll
  for (int p = 0; p < 32; ++p) {
    const int li = p * 256 + tid;
    const int f = li >> 6, nn = li & 63;
    const int u16 = nn & 15, gg = (nn >> 4) & 3;
    const int nsrc = gg * 1024 + ugrp * 16 + u16;
    sW[f][nn] = W[(size_t)f * N4 + nsrc];
  }
  __syncthreads();

  const int tx = tid & 15;
  const int ty = tid >> 4;
  float acc[4][4] = {};
  for (int f = 0; f < 128; ++f) {
    float a[4], b[4];
#pragma unroll
    for (int j = 0; j < 4; ++j) a[j] = sWd[tx * 4 + j][f];
#pragma unroll
    for (int i = 0; i < 4; ++i) b[i] = sW[f][ty * 4 + i];
#pragma unroll
    for (int i = 0; i < 4; ++i)
#pragma unroll
      for (int j = 0; j < 4; ++j) acc[i][j] += a[j] * b[i];
  }

#pragma unroll
  for (int i = 0; i < 4; ++i) {
    const int np = n0 + ty * 4 + i;
    const int u16 = np & 15, gg = (np >> 4) & 3;
    const int nsrc = gg * 1024 + ugrp * 16 + u16;
    const int cf = np >> 4;
#pragma unroll
    for (int j = 0; j < 4; ++j) {
      const int k = k0 + tx * 4 + j;
      const float v = rW[(size_t)k * N4 + nsrc] + acc[i][j];
      const int kc = k >> 5, lane = ((k >> 3) & 3) * 16 + (np & 15), e = k & 7;
      Wp2F[(((size_t)cf * 32 + kc) * 64 + lane) * 8 + e] = f2bf(v);
    }
  }
}

// ---------------- fused LSTM step ----------------
// 128x128 tile, 4 waves (64x64 subtile each), K_STEP=64.
// A (x/h) via LDS (double-buffered, swizzled); B (weights) direct global->reg
// from fragment-ordered WpF. Counted vmcnt pipeline, raw barriers.
// KT: K length; NKS: WpF kc-stride; HASX: x-part present; ZC: c==0 (t=0).
template<int KT, int NKS, bool HASX, bool ZC>
__global__ __launch_bounds__(256, 2)
void lstm_step_kernel(const ushort* __restrict__ Xc,   // [B][128] bf16
                      const ushort* __restrict__ Hin,  // [B][1024] bf16
                      const ushort* __restrict__ WpF,  // fragment-ordered weights
                      const float* __restrict__ bias,  // [4096] fp32, orig gate order
                      float* __restrict__ CF,          // fragment-ordered c state
                      ushort* __restrict__ Hout) {     // [B][1024] bf16
  __shared__ alignas(16) ushort sA[2 * 8192];          // 2 bufs x [2 kk][128 r][32 k']

  const int bid = blockIdx.x;
  const int wg = (bid & 7) * 64 + (bid >> 3);   // bijective XCD chunk swizzle (512%8==0)
  const int bx = wg & 15, by = wg >> 4;
  const int bm = bx * 128;
  const int bnf = by * 8;                        // B col-frag base (128 cols = 8 frags)

  const int tid = threadIdx.x;
  const int wid = tid >> 6;
  const int l = tid & 63;
  const int wr = wid >> 1;     // 0..1: rows wr*64
  const int wc = wid & 1;      // 0..1: cols wc*64

  const int rloc = l >> 2;
  const int slot = l & 3;
  const int gsw = slot ^ ((rloc >> 1) & 3);
  const int l15 = l & 15;
  const int kg = l >> 4;
  const int nfbase = bnf + wc * 4;

  constexpr int NT = KT / 64;

  f32x4 acc[4][4] = {};
  bf16x8 bv0[2][4], bv1[2][4];

  // c-state prefetch (fragment-ordered: coalesced float4)
  const int R = bx * 2 + wr;            // 0..31
  const int U = by * 2 + wc;            // 0..63
  const size_t cfbase = (((size_t)R * 64 + U) * 64 + l) * 16;
  f32x4 cpre[4];
  if (!ZC) {
#pragma unroll
    for (int m = 0; m < 4; ++m)
      cpre[m] = *reinterpret_cast<const f32x4*>(CF + cfbase + m * 4);
  }

  auto STAGE_A = [&](int t) {
    const int bufofs = (t & 1) * 8192;
    const int k0base = t * 64;
#pragma unroll
    for (int q = 0; q < 4; ++q) {
      const int c = wid * 4 + q;          // 0..15
      const int r = (c & 7) * 16 + rloc;
      const int k0s = k0base + (c >> 3) * 32;
      const ushort* src;
      if (HASX && k0s < FEAT) src = Xc + (size_t)(bm + r) * FEAT + k0s + gsw * 8;
      else                    src = Hin + (size_t)(bm + r) * UNITS + (k0s - (HASX ? FEAT : 0)) + gsw * 8;
      gload_lds16(src, &sA[bufofs + c * 512]);
    }
  };

  auto LOADB = [&](int t, bf16x8 (&bv)[2][4]) {
#pragma unroll
    for (int kk = 0; kk < 2; ++kk)
#pragma unroll
      for (int n = 0; n < 4; ++n) {
        const size_t kc = (size_t)(t * 2 + kk);
        bv[kk][n] = *reinterpret_cast<const bf16x8*>(
            WpF + (((size_t)(nfbase + n) * NKS + kc) * 64 + l) * 8);
      }
  };

  auto COMPUTE = [&](int t, bf16x8 (&bv)[2][4]) {
    const int bufofs = (t & 1) * 8192;
    bf16x8 av[2][4];
#pragma unroll
    for (int kk = 0; kk < 2; ++kk)
#pragma unroll
      for (int m = 0; m < 4; ++m) {
        const int r = wr * 64 + m * 16 + l15;
        const int sph = kg ^ ((r >> 1) & 3);
        av[kk][m] = *reinterpret_cast<const bf16x8*>(&sA[bufofs + kk * 4096 + r * 32 + sph * 8]);
      }
    __builtin_amdgcn_s_setprio(1);
#pragma unroll
    for (int kk = 0; kk < 2; ++kk)
#pragma unroll
      for (int m = 0; m < 4; ++m)
#pragma unroll
        for (int n = 0; n < 4; ++n)
          acc[m][n] = __builtin_amdgcn_mfma_f32_16x16x32_bf16(av[kk][m], bv[kk][n], acc[m][n], 0, 0, 0);
    __builtin_amdgcn_s_setprio(0);
  };

  auto ITER = [&](int t, bf16x8 (&bvU)[2][4], bf16x8 (&bvL)[2][4], bool last) {
    if (!last) {
      STAGE_A(t + 1);       // 4 gload_lds per wave
      LOADB(t + 1, bvL);    // 8 global b128 per wave
    }
    __builtin_amdgcn_sched_barrier(0);
    if (!last) asm volatile("s_waitcnt vmcnt(12)" ::: "memory");
    else       asm volatile("s_waitcnt vmcnt(0)" ::: "memory");
    asm volatile("s_barrier" ::: "memory");
    COMPUTE(t, bvU);
    asm volatile("s_barrier" ::: "memory");
  };

  // prologue
  STAGE_A(0);
  LOADB(0, bv0);

  for (int tp = 0; tp < (NT - 2) / 2; ++tp) {
    ITER(2 * tp, bv0, bv1, false);
    ITER(2 * tp + 1, bv1, bv0, false);
  }
  ITER(NT - 2, bv0, bv1, false);   // NT even for all instantiations
  ITER(NT - 1, bv1, bv0, true);

  // ---- epilogue: gates + state update ----
  const int unit = U * 16 + l15;
  const float bi = bias[unit];
  const float bf_ = bias[1024 + unit];
  const float bg = bias[2048 + unit];
  const float bo = bias[3072 + unit];

#pragma unroll
  for (int m = 0; m < 4; ++m) {
    const int rowb = bm + wr * 64 + m * 16 + kg * 4;
    f32x4 cout;
#pragma unroll
    for (int j = 0; j < 4; ++j) {
      const float i_ = sigm(acc[m][0][j] + bi);
      const float f_ = sigm(acc[m][1][j] + bf_);
      const float g_ = tanh_f(acc[m][2][j] + bg);
      const float o_ = sigm(acc[m][3][j] + bo);
      const float cn = ZC ? (i_ * g_) : (f_ * cpre[m][j] + i_ * g_);
      cout[j] = cn;
      Hout[(size_t)(rowb + j) * UNITS + unit] = f2bf(o_ * tanh_f(cn));
    }
    *reinterpret_cast<f32x4*>(CF + cfbase + m * 4) = cout;
  }
}

// ---------------- batched dense: out[b][s][f] = Hall[s][b] . Wd[:,f] + db[f] ----------------
__global__ __launch_bounds__(256)
void dense_all_kernel(const ushort* __restrict__ Hall,  // [24][2048][1024] bf16
                      const ushort* __restrict__ Wdt,   // [128][1024] bf16
                      const float* __restrict__ db,
                      float* __restrict__ out) {        // [2048][24][128] fp32
  __shared__ alignas(16) ushort sA[2][64 * 32];
  __shared__ alignas(16) ushort sB[2][128 * 32];

  const int bm = blockIdx.x * 64;
  const int tid = threadIdx.x;
  const int wid = tid >> 6;
  const int l = tid & 63;
  const int wr = wid >> 1;
  const int wc = wid & 1;

  const int rloc = l >> 2;
  const int slot = l & 3;
  const int gsw = slot ^ ((rloc >> 1) & 3);
  const int l15 = l & 15;
  const int kg = l >> 4;

  f32x4 acc[2][4] = {};

  auto STAGE = [&](int k0s, int bsel) {
#pragma unroll
    for (int q = 0; q < 3; ++q) {
      const int c = wid * 3 + q;   // 0..11: 0-3 sA, 4-11 sB
      if (c < 4) {
        const int r = c * 16 + rloc;
        gload_lds16(Hall + (size_t)(bm + r) * UNITS + k0s + gsw * 8, &sA[bsel][c * 512]);
      } else {
        const int cb = c - 4;
        const int r = cb * 16 + rloc;
        gload_lds16(Wdt + (size_t)r * UNITS + k0s + gsw * 8, &sB[bsel][cb * 512]);
      }
    }
  };

  STAGE(0, 0);
  __syncthreads();
  int cur = 0;
  for (int t = 0; t < 32; ++t) {
    if (t + 1 < 32) STAGE((t + 1) * 32, cur ^ 1);

    bf16x8 av[2], bv[4];
#pragma unroll
    for (int m = 0; m < 2; ++m) {
      const int r = wr * 32 + m * 16 + l15;
      const int sph = kg ^ ((r >> 1) & 3);
      av[m] = *reinterpret_cast<const bf16x8*>(&sA[cur][r * 32 + sph * 8]);
    }
#pragma unroll
    for (int n = 0; n < 4; ++n) {
      const int r = wc * 64 + n * 16 + l15;
      const int sph = kg ^ ((r >> 1) & 3);
      bv[n] = *reinterpret_cast<const bf16x8*>(&sB[cur][r * 32 + sph * 8]);
    }
#pragma unroll
    for (int m = 0; m < 2; ++m)
#pragma unroll
      for (int n = 0; n < 4; ++n)
        acc[m][n] = __builtin_amdgcn_mfma_f32_16x16x32_bf16(av[m], bv[n], acc[m][n], 0, 0, 0);

    __syncthreads();
    cur ^= 1;
  }

#pragma unroll
  for (int n = 0; n < 4; ++n) {
    const int f = wc * 64 + n * 16 + l15;
    const float bb = db[f];
#pragma unroll
    for (int m = 0; m < 2; ++m) {
#pragma unroll
      for (int j = 0; j < 4; ++j) {
        const int r = bm + wr * 32 + m * 16 + kg * 4 + j;
        const int s = r >> 11, b = r & 2047;
        out[((size_t)b * OUT_STEPS + s) * FEAT + f] = acc[m][n][j] + bb;
      }
    }
  }
}

// ---------------- launch ----------------
extern "C" void kernel_launch(void* const* d_in, const int* in_sizes, int n_in,
                              void* d_out, int out_size, void* d_ws, size_t ws_size,
                              hipStream_t stream) {
  const float* inputs  = (const float*)d_in[0];
  const float* kernelW = (const float*)d_in[1];
  const float* recW    = (const float*)d_in[2];
  const float* bias    = (const float*)d_in[3];
  const float* dw      = (const float*)d_in[4];
  const float* db      = (const float*)d_in[5];
  float* out = (float*)d_out;

  char* ws = (char*)d_ws;
  float*  CF   = (float*)ws;                                   // 8 MB (fragment-ordered c)
  ushort* Xb   = (ushort*)(ws + 8388608);                      // 24 MB (warmup only)
  ushort* Wp2F = Xb;                                           // 8 MB, aliases Xb
  ushort* Hb0  = (ushort*)(ws + 33554432);                     // 4 MB
  ushort* Hb1  = (ushort*)(ws + 37748736);                     // 4 MB
  ushort* WpF  = (ushort*)(ws + 41943040);                     // 9 MB
  ushort* Wdt  = (ushort*)(ws + 51380224);                     // 256 KB
  float*  b2   = (float*)(ws + 51642368);                      // 16 KB
  ushort* Hall = (ushort*)(ws + 51658752);                     // 96 MB: [24][2048][1024]
  ushort* Hb[2] = {Hb0, Hb1};
  const size_t HSLOT = (size_t)BATCH * UNITS;

  convert_inputs_kernel<<<TSEQ * BATCH * FEAT / 1024, 256, 0, stream>>>(inputs, Xb);
  prep_wF_kernel<<<(N4 / 16) * 36 * 64 / 256, 256, 0, stream>>>(kernelW, recW, WpF);
  prep_wd_kernel<<<FEAT * UNITS / 256, 256, 0, stream>>>(dw, Wdt);
  prep_b2_kernel<<<N4 / 256, 256, 0, stream>>>(bias, db, kernelW, b2);

  // t = 0: c = h = 0 -> K=128 (x only), no C read, no memsets needed.
  lstm_step_kernel<128, 36, true, true><<<512, 256, 0, stream>>>(
      Xb, Hb0 /*unused*/, WpF, bias, CF, Hb1);
  int cur = 1;
  for (int t = 1; t < TSEQ; ++t) {
    ushort* hout = (t == TSEQ - 1) ? Hall : Hb[cur ^ 1];
    lstm_step_kernel<KTOT, 36, true, false><<<512, 256, 0, stream>>>(
        Xb + (size_t)t * BATCH * FEAT, Hb[cur], WpF, bias, CF, hout);
    cur ^= 1;
  }
  // Wp2F aliases Xb — build only after warmup consumed Xb.
  prep_u_kernel<<<dim3(64, 16), 256, 0, stream>>>(dw, kernelW, recW, Wp2F);

  for (int s = 1; s < OUT_STEPS; ++s) {
    lstm_step_kernel<UNITS, 32, false, false><<<512, 256, 0, stream>>>(
        nullptr, Hall + (size_t)(s - 1) * HSLOT, Wp2F, b2, CF, Hall + (size_t)s * HSLOT);
  }
  dense_all_kernel<<<(OUT_STEPS * BATCH) / 64, 256, 0, stream>>>(Hall, Wdt, db, out);
}